// Round 3
// baseline (478.455 us; speedup 1.0000x reference)
//
#include <hip/hip_runtime.h>
#include <hip/hip_fp16.h>

typedef _Float16 f16;
typedef _Float16 f16x8 __attribute__((ext_vector_type(8)));
typedef _Float16 f16x4 __attribute__((ext_vector_type(4)));
typedef float f32x4 __attribute__((ext_vector_type(4)));

#define AS1 __attribute__((address_space(1)))
#define AS3 __attribute__((address_space(3)))

__device__ __forceinline__ void g2l16(const void* g, void* l) {
  __builtin_amdgcn_global_load_lds((const AS1 void*)g, (AS3 void*)l, 16, 0, 0);
}

// bijective XCD-chunk swizzle (requires nwg % 8 == 0; true for all our grids)
__device__ __forceinline__ void xcd_swz(int& bx, int& by, int& bz) {
  int gx = gridDim.x, gy = gridDim.y;
  int nwg = gx * gy * gridDim.z;
  int lin = (blockIdx.z * gy + blockIdx.y) * gx + blockIdx.x;
  int swz = (lin & 7) * (nwg >> 3) + (lin >> 3);
  bx = swz % gx;
  int t = swz / gx;
  by = t % gy;
  bz = t / gy;
}

// ---------------- build X = [x_r | x_i] as fp16, [16384, 512] ----------------
__global__ __launch_bounds__(256) void build_x(const float* __restrict__ qr,
                                               const float* __restrict__ qi,
                                               f16* __restrict__ X) {
  long i = (long)blockIdx.x * 256 + threadIdx.x;
  long e = i * 4;
  int m = (int)(e >> 9);
  int k = (int)(e & 511);
  const float* src = (k < 256) ? (qr + (long)m * 256 + k)
                               : (qi + (long)m * 256 + (k - 256));
  float4 v = *(const float4*)src;
  f16x4 h = {(f16)v.x, (f16)v.y, (f16)v.z, (f16)v.w};
  *(f16x4*)(X + e) = h;
}

// ------- build Wbig [1536, 512] fp16, rows n = [qr,qi,kr,ki,vr,vi] blocks -----
__global__ __launch_bounds__(256) void build_w(const float* __restrict__ wqr,
                                               const float* __restrict__ wqi,
                                               const float* __restrict__ wkr,
                                               const float* __restrict__ wki,
                                               const float* __restrict__ wvr,
                                               const float* __restrict__ wvi,
                                               f16* __restrict__ W) {
  long i = (long)blockIdx.x * 256 + threadIdx.x;
  long e = i * 4;
  int n = (int)(e >> 9);
  int k = (int)(e & 511);
  int sel = n >> 8;
  int row = n & 255;
  int k2 = k & 255;
  bool hi = (k >= 256);
  const float *Wr, *Wi;
  if ((sel >> 1) == 0)      { Wr = wqr; Wi = wqi; }
  else if ((sel >> 1) == 1) { Wr = wkr; Wi = wki; }
  else                      { Wr = wvr; Wi = wvi; }
  const float* src;
  float sgn = 1.0f;
  if ((sel & 1) == 0) {
    if (!hi) src = Wr + (long)row * 256 + k2;
    else   { src = Wi + (long)row * 256 + k2; sgn = -1.0f; }
  } else {
    if (!hi) src = Wi + (long)row * 256 + k2;
    else     src = Wr + (long)row * 256 + k2;
  }
  float4 v = *(const float4*)src;
  f16x4 h = {(f16)(sgn * v.x), (f16)(sgn * v.y), (f16)(sgn * v.z), (f16)(sgn * v.w)};
  *(f16x4*)(W + e) = h;
}

// ---------------- generic NT GEMM, fp16 A/B, 128x128 tile, BK=64 ----------------
// LDS 16B-slot XOR swizzle (stored[r][c8] = logical[r][c8 ^ (r&7)]), staged via
// global_load_lds with pre-swizzled per-lane SOURCE address.
// MODE 0: C = fp16, ldc 1536 (projection output P)
// MODE 1: C = fp32 * scale (raw scores) + per-64-col-tile softmax stats (m_t, l_t)
template <int MODE>
__global__ __launch_bounds__(256) void gemm_nt(const f16* __restrict__ A, int lda, long astr,
                                               const f16* __restrict__ B, int ldb, long bstr,
                                               int K, float scale,
                                               void* __restrict__ C0, long cstr,
                                               float2* __restrict__ stats) {
  __shared__ __align__(16) f16 As[128 * 64];
  __shared__ __align__(16) f16 Bs[128 * 64];
  int bx, by, bz;
  xcd_swz(bx, by, bz);
  const f16* Ab = A + (long)bz * astr;
  const f16* Bb = B + (long)bz * bstr;
  const int tid = threadIdx.x;
  const int wave = tid >> 6, lane = tid & 63;
  const int bm = by * 128, bn = bx * 128;
  const int wm = (wave >> 1) * 64, wn = (wave & 1) * 64;
  const int lr = lane & 15, lg = lane >> 4;

  const int srow = wave * 8 + (lane >> 3);
  const int sk = ((lane & 7) ^ (lane >> 3)) * 8;

  f32x4 acc[4][4] = {};

  for (int kt = 0; kt < K; kt += 64) {
#pragma unroll
    for (int it = 0; it < 4; ++it) {
      int r = srow + it * 32;
      g2l16(Ab + (long)(bm + r) * lda + kt + sk, (char*)As + it * 4096 + wave * 1024);
      g2l16(Bb + (long)(bn + r) * ldb + kt + sk, (char*)Bs + it * 4096 + wave * 1024);
    }
    __syncthreads();
#pragma unroll
    for (int kk = 0; kk < 2; ++kk) {
      f16x8 af[4], bf[4];
#pragma unroll
      for (int f = 0; f < 4; ++f) {
        int sw = ((kk * 4 + lg) ^ (lr & 7)) * 8;
        af[f] = *(const f16x8*)(As + (wm + f * 16 + lr) * 64 + sw);
        bf[f] = *(const f16x8*)(Bs + (wn + f * 16 + lr) * 64 + sw);
      }
#pragma unroll
      for (int fm = 0; fm < 4; ++fm)
#pragma unroll
        for (int fn = 0; fn < 4; ++fn)
          acc[fm][fn] = __builtin_amdgcn_mfma_f32_16x16x32_f16(af[fm], bf[fn], acc[fm][fn], 0, 0, 0);
    }
    __syncthreads();
  }

#pragma unroll
  for (int fm = 0; fm < 4; ++fm) {
#pragma unroll
    for (int fn = 0; fn < 4; ++fn) {
#pragma unroll
      for (int r = 0; r < 4; ++r) {
        int row = bm + wm + fm * 16 + lg * 4 + r;
        int col = bn + wn + fn * 16 + lr;
        float v = acc[fm][fn][r];
        if (MODE == 0) {
          ((f16*)C0)[(long)row * 1536 + col] = (f16)v;
        } else {
          ((float*)C0)[(long)bz * cstr + (long)row * 4096 + col] = v * scale;
        }
      }
    }
  }

  if (MODE == 1) {
    // per-row stats over this wave's 64-col tile: nt in [0,64)
    const int nt = bx * 2 + (wn >> 6);
#pragma unroll
    for (int fm = 0; fm < 4; ++fm) {
#pragma unroll
      for (int r = 0; r < 4; ++r) {
        float v0 = acc[fm][0][r] * scale, v1 = acc[fm][1][r] * scale;
        float v2 = acc[fm][2][r] * scale, v3 = acc[fm][3][r] * scale;
        float mt = fmaxf(fmaxf(v0, v1), fmaxf(v2, v3));
#pragma unroll
        for (int off = 8; off >= 1; off >>= 1) mt = fmaxf(mt, __shfl_xor(mt, off));
        float lt = __expf(v0 - mt) + __expf(v1 - mt) + __expf(v2 - mt) + __expf(v3 - mt);
#pragma unroll
        for (int off = 8; off >= 1; off >>= 1) lt += __shfl_xor(lt, off);
        if (lr == 0) {
          int row = bm + wm + fm * 16 + lg * 4 + r;
          stats[((long)bz * 4096 + row) * 64 + nt] = make_float2(mt, lt);
        }
      }
    }
  }
}

// ------------- transpose V block of P into VT [4][512][4096] fp16 -------------
__global__ __launch_bounds__(256) void build_vt(const f16* __restrict__ P,
                                                f16* __restrict__ VT) {
  __shared__ f16 t[64][66];
  const int tid = threadIdx.x;
  const long b = blockIdx.z;
  const f16* src = P + (b * 4096 + (long)blockIdx.x * 64) * 1536 + 1024 + blockIdx.y * 64;
#pragma unroll
  for (int it = 0; it < 16; ++it) {
    int lin = it * 256 + tid;
    int i = lin >> 6, j = lin & 63;
    t[i][j] = src[(long)i * 1536 + j];
  }
  __syncthreads();
  f16* dst = VT + (b * 512 + (long)blockIdx.y * 64) * 4096 + blockIdx.x * 64;
#pragma unroll
  for (int it = 0; it < 16; ++it) {
    int lin = it * 256 + tid;
    int i = lin >> 6, j = lin & 63;
    dst[(long)i * 4096 + j] = t[j][i];
  }
}

// --------- merge per-tile stats: m = max m_t ; l = sum l_t * exp(m_t - m) ---------
__global__ __launch_bounds__(256) void merge_stats(const float2* __restrict__ stats,
                                                   float2* __restrict__ ml) {
  long row = (long)blockIdx.x * 256 + threadIdx.x;  // 0..16383
  const float2* s = stats + row * 64;
  float m = -1e30f;
#pragma unroll 8
  for (int i = 0; i < 64; ++i) m = fmaxf(m, s[i].x);
  float l = 0.0f;
#pragma unroll 8
  for (int i = 0; i < 64; ++i) l += s[i].y * __expf(s[i].x - m);
  ml[row] = make_float2(m, l);
}

// ------ fused normalize + PV: attn (raw->normalized, in place) , out = P @ V ------
// block: 64 rows x full N=512, 512 threads (8 waves 2Mx4N), K-loop over 4096, BK=64
__global__ __launch_bounds__(512) void pv_fused(const float2* __restrict__ ml,
                                                float* __restrict__ attn,   // in: raw scores
                                                const f16* __restrict__ VT,
                                                float* __restrict__ outR,
                                                float* __restrict__ outI) {
  __shared__ __align__(16) f16 Ps[64 * 64];
  __shared__ __align__(16) f16 Bs[512 * 64];
  // XCD swizzle over 256 blocks: (rowtile 64) x (batch 4)
  int lin = blockIdx.y * 64 + blockIdx.x;
  int swz = (lin & 7) * 32 + (lin >> 3);
  int bx = swz & 63, b = swz >> 6;
  const int bm = bx * 64;
  float* Ab = attn + (long)b * 4096 * 4096;
  const f16* Bb = VT + (long)b * 512 * 4096;
  const int tid = threadIdx.x;
  const int wave = tid >> 6, lane = tid & 63;
  const int wm2 = (wave >> 2) * 32;   // 0 / 32
  const int wn2 = (wave & 3) * 128;   // 0 / 128 / 256 / 384
  const int lr = lane & 15, lg = lane >> 4;

  // staging roles
  const int prow = tid >> 3;          // 0..63 (score row within tile)
  const int pc8 = tid & 7;            // 8-col group
  const int vsw = ((lane & 7) ^ ((lane >> 3) & 7)) * 8;  // pre-swizzled V source offset
  float2 mlv = ml[(long)b * 4096 + bm + prow];
  const float mrow = mlv.x;
  const float invl = 1.0f / mlv.y;

  f32x4 acc[2][8] = {};

  for (int kt = 0; kt < 4096; kt += 64) {
    // issue V staging first (overlaps with score load + exp)
#pragma unroll
    for (int i = 0; i < 8; ++i) {
      int r = i * 64 + wave * 8 + (lane >> 3);
      g2l16(Bb + (long)r * 4096 + kt + vsw, (char*)Bs + i * 8192 + wave * 1024);
    }
    // normalize 8 scores, write attn in place, store f16 row-chunk to LDS
    float* srow = Ab + (long)(bm + prow) * 4096 + kt + pc8 * 8;
    float4 s0 = *(const float4*)srow;
    float4 s1 = *(const float4*)(srow + 4);
    float p0 = __expf(s0.x - mrow) * invl, p1 = __expf(s0.y - mrow) * invl;
    float p2 = __expf(s0.z - mrow) * invl, p3 = __expf(s0.w - mrow) * invl;
    float p4 = __expf(s1.x - mrow) * invl, p5 = __expf(s1.y - mrow) * invl;
    float p6 = __expf(s1.z - mrow) * invl, p7 = __expf(s1.w - mrow) * invl;
    float4 w0 = {p0, p1, p2, p3}, w1 = {p4, p5, p6, p7};
    *(float4*)srow = w0;
    *(float4*)(srow + 4) = w1;
    f16x8 h = {(f16)p0, (f16)p1, (f16)p2, (f16)p3, (f16)p4, (f16)p5, (f16)p6, (f16)p7};
    *(f16x8*)(Ps + prow * 64 + (pc8 ^ (prow & 7)) * 8) = h;
    __syncthreads();
#pragma unroll
    for (int kk = 0; kk < 2; ++kk) {
      f16x8 af[2];
#pragma unroll
      for (int fm = 0; fm < 2; ++fm)
        af[fm] = *(const f16x8*)(Ps + (wm2 + fm * 16 + lr) * 64 + ((kk * 4 + lg) ^ (lr & 7)) * 8);
#pragma unroll
      for (int fg = 0; fg < 2; ++fg) {
        f16x8 bf[4];
#pragma unroll
        for (int f = 0; f < 4; ++f) {
          int n = wn2 + fg * 64 + f * 16 + lr;
          bf[f] = *(const f16x8*)(Bs + n * 64 + ((kk * 4 + lg) ^ (lr & 7)) * 8);
        }
#pragma unroll
        for (int fm = 0; fm < 2; ++fm)
#pragma unroll
          for (int f = 0; f < 4; ++f)
            acc[fm][fg * 4 + f] =
                __builtin_amdgcn_mfma_f32_16x16x32_f16(af[fm], bf[f], acc[fm][fg * 4 + f], 0, 0, 0);
      }
    }
    __syncthreads();
  }

#pragma unroll
  for (int fm = 0; fm < 2; ++fm) {
#pragma unroll
    for (int fn = 0; fn < 8; ++fn) {
#pragma unroll
      for (int r = 0; r < 4; ++r) {
        int row = bm + wm2 + fm * 16 + lg * 4 + r;
        int col = wn2 + fn * 16 + lr;
        float v = acc[fm][fn][r];
        long o = ((long)b * 4096 + row) * 256 + (col & 255);
        if (col < 256) outR[o] = v; else outI[o] = v;
      }
    }
  }
}

extern "C" void kernel_launch(void* const* d_in, const int* in_sizes, int n_in,
                              void* d_out, int out_size, void* d_ws, size_t ws_size,
                              hipStream_t stream) {
  const float* qr  = (const float*)d_in[0];
  const float* qi  = (const float*)d_in[1];
  const float* wqr = (const float*)d_in[2];
  const float* wqi = (const float*)d_in[3];
  const float* wkr = (const float*)d_in[4];
  const float* wki = (const float*)d_in[5];
  const float* wvr = (const float*)d_in[6];
  const float* wvi = (const float*)d_in[7];

  float* outR = (float*)d_out;                       // [4,4096,256]
  float* outI = outR + (size_t)4 * 4096 * 256;       // [4,4096,256]
  float* attn = outI + (size_t)4 * 4096 * 256;       // [4,4096,4096] raw scores -> normalized

  char* ws = (char*)d_ws;
  f16* X  = (f16*)ws;                                              // [16384,512]   16 MB (dead after proj -> stats)
  f16* W  = (f16*)(ws + (size_t)16384 * 512 * 2);                  // [1536,512]    1.5 MB (dead after proj -> ml)
  f16* P  = (f16*)(ws + (size_t)16384 * 512 * 2 + (size_t)1536 * 512 * 2);  // [16384,1536] 48 MB
  f16* VT = (f16*)(ws + (size_t)16384 * 512 * 2 + (size_t)1536 * 512 * 2 +
                   (size_t)16384 * 1536 * 2);                      // [4,512,4096]  16 MB
  float2* stats = (float2*)X;                                      // [16384][64]   8 MB
  float2* ml    = (float2*)W;                                      // [16384]       128 KB

  build_x<<<8192, 256, 0, stream>>>(qr, qi, X);
  build_w<<<768, 256, 0, stream>>>(wqr, wqi, wkr, wki, wvr, wvi, W);

  // P = X @ Wbig^T : M=16384, N=1536, K=512
  gemm_nt<0><<<dim3(12, 128, 1), 256, 0, stream>>>(X, 512, 0L, W, 512, 0L, 512, 1.0f,
                                                   (void*)P, 0L, nullptr);

  build_vt<<<dim3(64, 8, 4), 256, 0, stream>>>(P, VT);

  // raw scores + per-tile stats : per batch M=N=4096, K=512
  gemm_nt<1><<<dim3(32, 32, 4), 256, 0, stream>>>(P, 1536, (long)4096 * 1536,
                                                  P + 512, 1536, (long)4096 * 1536,
                                                  512, 0.0625f,
                                                  (void*)attn, (long)4096 * 4096, stats);

  merge_stats<<<64, 256, 0, stream>>>(stats, ml);

  // fused normalize + PV
  pv_fused<<<dim3(64, 4, 1), 512, 0, stream>>>(ml, attn, VT, outR, outI);
}

// Round 4
// 435.003 us; speedup vs baseline: 1.0999x; 1.0999x over previous
//
#include <hip/hip_runtime.h>
#include <hip/hip_fp16.h>

typedef _Float16 f16;
typedef _Float16 f16x8 __attribute__((ext_vector_type(8)));
typedef _Float16 f16x4 __attribute__((ext_vector_type(4)));
typedef float f32x4 __attribute__((ext_vector_type(4)));

#define AS1 __attribute__((address_space(1)))
#define AS3 __attribute__((address_space(3)))

__device__ __forceinline__ void g2l16(const void* g, void* l) {
  __builtin_amdgcn_global_load_lds((const AS1 void*)g, (AS3 void*)l, 16, 0, 0);
}

// bijective XCD-chunk swizzle (requires nwg % 8 == 0; true for all our grids)
__device__ __forceinline__ void xcd_swz(int& bx, int& by, int& bz) {
  int gx = gridDim.x, gy = gridDim.y;
  int nwg = gx * gy * gridDim.z;
  int lin = (blockIdx.z * gy + blockIdx.y) * gx + blockIdx.x;
  int swz = (lin & 7) * (nwg >> 3) + (lin >> 3);
  bx = swz % gx;
  int t = swz / gx;
  by = t % gy;
  bz = t / gy;
}

// ---------------- build X = [x_r | x_i] as fp16, [16384, 512] ----------------
__global__ __launch_bounds__(256) void build_x(const float* __restrict__ qr,
                                               const float* __restrict__ qi,
                                               f16* __restrict__ X) {
  long i = (long)blockIdx.x * 256 + threadIdx.x;
  long e = i * 4;
  int m = (int)(e >> 9);
  int k = (int)(e & 511);
  const float* src = (k < 256) ? (qr + (long)m * 256 + k)
                               : (qi + (long)m * 256 + (k - 256));
  float4 v = *(const float4*)src;
  f16x4 h = {(f16)v.x, (f16)v.y, (f16)v.z, (f16)v.w};
  *(f16x4*)(X + e) = h;
}

// ------- build Wbig [1536, 512] fp16, rows n = [qr,qi,kr,ki,vr,vi] blocks -----
__global__ __launch_bounds__(256) void build_w(const float* __restrict__ wqr,
                                               const float* __restrict__ wqi,
                                               const float* __restrict__ wkr,
                                               const float* __restrict__ wki,
                                               const float* __restrict__ wvr,
                                               const float* __restrict__ wvi,
                                               f16* __restrict__ W) {
  long i = (long)blockIdx.x * 256 + threadIdx.x;
  long e = i * 4;
  int n = (int)(e >> 9);
  int k = (int)(e & 511);
  int sel = n >> 8;
  int row = n & 255;
  int k2 = k & 255;
  bool hi = (k >= 256);
  const float *Wr, *Wi;
  if ((sel >> 1) == 0)      { Wr = wqr; Wi = wqi; }
  else if ((sel >> 1) == 1) { Wr = wkr; Wi = wki; }
  else                      { Wr = wvr; Wi = wvi; }
  const float* src;
  float sgn = 1.0f;
  if ((sel & 1) == 0) {
    if (!hi) src = Wr + (long)row * 256 + k2;
    else   { src = Wi + (long)row * 256 + k2; sgn = -1.0f; }
  } else {
    if (!hi) src = Wi + (long)row * 256 + k2;
    else     src = Wr + (long)row * 256 + k2;
  }
  float4 v = *(const float4*)src;
  f16x4 h = {(f16)(sgn * v.x), (f16)(sgn * v.y), (f16)(sgn * v.z), (f16)(sgn * v.w)};
  *(f16x4*)(W + e) = h;
}

// ---------------- generic NT GEMM, fp16 A/B, 128x128 tile, BK=64 ----------------
// MODE 0: C = fp16, ldc 1536 (projection output P)
// MODE 1: C = fp32 * scale (raw scores) + per-64-col-tile softmax stats [nt][16384]
template <int MODE>
__global__ __launch_bounds__(256) void gemm_nt(const f16* __restrict__ A, int lda, long astr,
                                               const f16* __restrict__ B, int ldb, long bstr,
                                               int K, float scale,
                                               void* __restrict__ C0, long cstr,
                                               float2* __restrict__ stats) {
  __shared__ __align__(16) f16 As[128 * 64];
  __shared__ __align__(16) f16 Bs[128 * 64];
  int bx, by, bz;
  xcd_swz(bx, by, bz);
  const f16* Ab = A + (long)bz * astr;
  const f16* Bb = B + (long)bz * bstr;
  const int tid = threadIdx.x;
  const int wave = tid >> 6, lane = tid & 63;
  const int bm = by * 128, bn = bx * 128;
  const int wm = (wave >> 1) * 64, wn = (wave & 1) * 64;
  const int lr = lane & 15, lg = lane >> 4;

  const int srow = wave * 8 + (lane >> 3);
  const int sk = ((lane & 7) ^ (lane >> 3)) * 8;

  f32x4 acc[4][4] = {};

  for (int kt = 0; kt < K; kt += 64) {
#pragma unroll
    for (int it = 0; it < 4; ++it) {
      int r = srow + it * 32;
      g2l16(Ab + (long)(bm + r) * lda + kt + sk, (char*)As + it * 4096 + wave * 1024);
      g2l16(Bb + (long)(bn + r) * ldb + kt + sk, (char*)Bs + it * 4096 + wave * 1024);
    }
    __syncthreads();
#pragma unroll
    for (int kk = 0; kk < 2; ++kk) {
      f16x8 af[4], bf[4];
#pragma unroll
      for (int f = 0; f < 4; ++f) {
        int sw = ((kk * 4 + lg) ^ (lr & 7)) * 8;
        af[f] = *(const f16x8*)(As + (wm + f * 16 + lr) * 64 + sw);
        bf[f] = *(const f16x8*)(Bs + (wn + f * 16 + lr) * 64 + sw);
      }
#pragma unroll
      for (int fm = 0; fm < 4; ++fm)
#pragma unroll
        for (int fn = 0; fn < 4; ++fn)
          acc[fm][fn] = __builtin_amdgcn_mfma_f32_16x16x32_f16(af[fm], bf[fn], acc[fm][fn], 0, 0, 0);
    }
    __syncthreads();
  }

#pragma unroll
  for (int fm = 0; fm < 4; ++fm) {
#pragma unroll
    for (int fn = 0; fn < 4; ++fn) {
#pragma unroll
      for (int r = 0; r < 4; ++r) {
        int row = bm + wm + fm * 16 + lg * 4 + r;
        int col = bn + wn + fn * 16 + lr;
        float v = acc[fm][fn][r];
        if (MODE == 0) {
          ((f16*)C0)[(long)row * 1536 + col] = (f16)v;
        } else {
          ((float*)C0)[(long)bz * cstr + (long)row * 4096 + col] = v * scale;
        }
      }
    }
  }

  if (MODE == 1) {
    const int nt = bx * 2 + (wn >> 6);
#pragma unroll
    for (int fm = 0; fm < 4; ++fm) {
#pragma unroll
      for (int r = 0; r < 4; ++r) {
        float v0 = acc[fm][0][r] * scale, v1 = acc[fm][1][r] * scale;
        float v2 = acc[fm][2][r] * scale, v3 = acc[fm][3][r] * scale;
        float mt = fmaxf(fmaxf(v0, v1), fmaxf(v2, v3));
#pragma unroll
        for (int off = 8; off >= 1; off >>= 1) mt = fmaxf(mt, __shfl_xor(mt, off));
        float lt = __expf(v0 - mt) + __expf(v1 - mt) + __expf(v2 - mt) + __expf(v3 - mt);
#pragma unroll
        for (int off = 8; off >= 1; off >>= 1) lt += __shfl_xor(lt, off);
        if (lr == 0) {
          int row = bm + wm + fm * 16 + lg * 4 + r;
          stats[(long)nt * 16384 + (long)bz * 4096 + row] = make_float2(mt, lt);  // [nt][row]
        }
      }
    }
  }
}

// ------------- transpose V block of P into VT [4][512][4096] fp16 -------------
__global__ __launch_bounds__(256) void build_vt(const f16* __restrict__ P,
                                                f16* __restrict__ VT) {
  __shared__ f16 t[64][66];
  const int tid = threadIdx.x;
  const long b = blockIdx.z;
  const f16* src = P + (b * 4096 + (long)blockIdx.x * 64) * 1536 + 1024 + blockIdx.y * 64;
#pragma unroll
  for (int it = 0; it < 16; ++it) {
    int lin = it * 256 + tid;
    int i = lin >> 6, j = lin & 63;
    t[i][j] = src[(long)i * 1536 + j];
  }
  __syncthreads();
  f16* dst = VT + (b * 512 + (long)blockIdx.y * 64) * 4096 + blockIdx.x * 64;
#pragma unroll
  for (int it = 0; it < 16; ++it) {
    int lin = it * 256 + tid;
    int i = lin >> 6, j = lin & 63;
    dst[(long)i * 4096 + j] = t[j][i];
  }
}

// --------- merge per-tile stats (layout [nt][16384], coalesced reads) ---------
__global__ __launch_bounds__(256) void merge_stats(const float2* __restrict__ stats,
                                                   float2* __restrict__ ml) {
  long row = (long)blockIdx.x * 256 + threadIdx.x;  // 0..16383
  float m = -1e30f;
#pragma unroll 8
  for (int i = 0; i < 64; ++i) m = fmaxf(m, stats[i * 16384 + row].x);
  float l = 0.0f;
#pragma unroll 8
  for (int i = 0; i < 64; ++i) {
    float2 s = stats[i * 16384 + row];
    l += s.y * __expf(s.x - m);
  }
  ml[row] = make_float2(m, l);
}

// ------ fused normalize + PV, software-pipelined ------
// block: 64 rows x N=512, 512 threads (8 waves 2Mx4N); K-loop 64 tiles of BK=64.
// Pipeline: scores prefetched 2 tiles ahead (regs), V g2l + P exp/LDS-write for
// tile t+1 overlap MFMA of tile t; double-buffered Bs/Ps; 1 barrier per tile.
__global__ __launch_bounds__(512) void pv_fused(const float2* __restrict__ ml,
                                                float* __restrict__ attn,   // raw -> normalized
                                                const f16* __restrict__ VT,
                                                float* __restrict__ outR,
                                                float* __restrict__ outI) {
  __shared__ __align__(16) f16 Ps0[64 * 64];
  __shared__ __align__(16) f16 Ps1[64 * 64];
  __shared__ __align__(16) f16 Bs0[512 * 64];
  __shared__ __align__(16) f16 Bs1[512 * 64];
  // swizzle: XCD k gets 32 consecutive works -> each batch owned by 2 XCDs (V L2-resident)
  int lin = blockIdx.y * 64 + blockIdx.x;
  int swz = (lin & 7) * 32 + (lin >> 3);
  int bx = swz & 63, b = swz >> 6;
  const int bm = bx * 64;
  float* Ab = attn + (long)b * 4096 * 4096;
  const f16* Bb = VT + (long)b * 512 * 4096;
  const int tid = threadIdx.x;
  const int wave = tid >> 6, lane = tid & 63;
  const int wm2 = (wave >> 2) * 32;
  const int wn2 = (wave & 3) * 128;
  const int lr = lane & 15, lg = lane >> 4;

  const int prow = tid >> 3;          // 0..63
  const int pc8 = tid & 7;            // 8-col group
  const int vrow = wave * 8 + (lane >> 3);
  const int vsw = ((lane & 7) ^ ((lane >> 3) & 7)) * 8;
  float2 mlv = ml[(long)b * 4096 + bm + prow];
  const float mrow = mlv.x;
  const float invl = 1.0f / mlv.y;

  float* const arow = Ab + (long)(bm + prow) * 4096 + pc8 * 8;
  const int pslot = (pc8 ^ (prow & 7)) * 8;

  f32x4 acc[2][8] = {};
  float4 sc00, sc01, sc10, sc11;  // 2-deep score prefetch slots

#define PV_EXP(SCA, SCB, PSBUF, KT)                                         \
  {                                                                         \
    float p0 = __expf(SCA.x - mrow) * invl, p1 = __expf(SCA.y - mrow) * invl; \
    float p2 = __expf(SCA.z - mrow) * invl, p3 = __expf(SCA.w - mrow) * invl; \
    float p4 = __expf(SCB.x - mrow) * invl, p5 = __expf(SCB.y - mrow) * invl; \
    float p6 = __expf(SCB.z - mrow) * invl, p7 = __expf(SCB.w - mrow) * invl; \
    float4 w0 = {p0, p1, p2, p3}, w1 = {p4, p5, p6, p7};                    \
    *(float4*)(arow + (KT)) = w0;                                           \
    *(float4*)(arow + (KT) + 4) = w1;                                       \
    f16x8 h = {(f16)p0, (f16)p1, (f16)p2, (f16)p3,                          \
               (f16)p4, (f16)p5, (f16)p6, (f16)p7};                         \
    *(f16x8*)(PSBUF + prow * 64 + pslot) = h;                               \
  }

#define PV_MFMA(PSBUF, BSBUF)                                               \
  {                                                                         \
    _Pragma("unroll")                                                       \
    for (int kk = 0; kk < 2; ++kk) {                                        \
      f16x8 af[2];                                                          \
      _Pragma("unroll")                                                     \
      for (int fm = 0; fm < 2; ++fm)                                        \
        af[fm] = *(const f16x8*)(PSBUF + (wm2 + fm * 16 + lr) * 64 +        \
                                 ((kk * 4 + lg) ^ (lr & 7)) * 8);           \
      _Pragma("unroll")                                                     \
      for (int fg = 0; fg < 2; ++fg) {                                      \
        f16x8 bf[4];                                                        \
        _Pragma("unroll")                                                   \
        for (int f = 0; f < 4; ++f) {                                       \
          int n = wn2 + fg * 64 + f * 16 + lr;                              \
          bf[f] = *(const f16x8*)(BSBUF + n * 64 +                          \
                                  ((kk * 4 + lg) ^ (lr & 7)) * 8);          \
        }                                                                   \
        _Pragma("unroll")                                                   \
        for (int fm = 0; fm < 2; ++fm)                                      \
          _Pragma("unroll")                                                 \
          for (int f = 0; f < 4; ++f)                                       \
            acc[fm][fg * 4 + f] = __builtin_amdgcn_mfma_f32_16x16x32_f16(   \
                af[fm], bf[f], acc[fm][fg * 4 + f], 0, 0, 0);               \
      }                                                                     \
    }                                                                       \
  }

#define PV_G2L(BSBUF, KT)                                                   \
  {                                                                         \
    _Pragma("unroll")                                                       \
    for (int i = 0; i < 8; ++i)                                             \
      g2l16(Bb + (long)(i * 64 + vrow) * 4096 + (KT) + vsw,                 \
            (char*)BSBUF + i * 8192 + wave * 1024);                         \
  }

// STEP at tile T (CUR = T&1): prefetch scores[T+2] -> slot CUR; g2l V[T+1] -> Bs[NXT];
// MFMA(Ps[CUR], Bs[CUR]); exp scores[T+1] (slot NXT) -> attn + Ps[NXT]; barrier.
#define PV_STEP(T, SA0, SA1, SB0, SB1, PSC, BSC, PSN, BSN)                  \
  {                                                                         \
    if ((T) + 2 < 64) {                                                     \
      SA0 = *(const float4*)(arow + ((T) + 2) * 64);                        \
      SA1 = *(const float4*)(arow + ((T) + 2) * 64 + 4);                    \
    }                                                                       \
    if ((T) + 1 < 64) PV_G2L(BSN, ((T) + 1) * 64)                           \
    PV_MFMA(PSC, BSC)                                                       \
    if ((T) + 1 < 64) PV_EXP(SB0, SB1, PSN, ((T) + 1) * 64)                 \
    __syncthreads();                                                        \
  }

  // prologue: tile0 scores -> slot0 (consumed now), tile1 -> slot1, V0 -> Bs0
  sc00 = *(const float4*)(arow + 0);
  sc01 = *(const float4*)(arow + 4);
  sc10 = *(const float4*)(arow + 64);
  sc11 = *(const float4*)(arow + 64 + 4);
  PV_G2L(Bs0, 0)
  PV_EXP(sc00, sc01, Ps0, 0)
  __syncthreads();

  for (int t2 = 0; t2 < 64; t2 += 2) {
    PV_STEP(t2,     sc00, sc01, sc10, sc11, Ps0, Bs0, Ps1, Bs1)
    PV_STEP(t2 + 1, sc10, sc11, sc00, sc01, Ps1, Bs1, Ps0, Bs0)
  }

#pragma unroll
  for (int fm = 0; fm < 2; ++fm) {
#pragma unroll
    for (int fn = 0; fn < 8; ++fn) {
#pragma unroll
      for (int r = 0; r < 4; ++r) {
        int row = bm + wm2 + fm * 16 + lg * 4 + r;
        int col = wn2 + fn * 16 + lr;
        float v = acc[fm][fn][r];
        long o = ((long)b * 4096 + row) * 256 + (col & 255);
        if (col < 256) outR[o] = v; else outI[o] = v;
      }
    }
  }
#undef PV_STEP
#undef PV_G2L
#undef PV_MFMA
#undef PV_EXP
}

extern "C" void kernel_launch(void* const* d_in, const int* in_sizes, int n_in,
                              void* d_out, int out_size, void* d_ws, size_t ws_size,
                              hipStream_t stream) {
  const float* qr  = (const float*)d_in[0];
  const float* qi  = (const float*)d_in[1];
  const float* wqr = (const float*)d_in[2];
  const float* wqi = (const float*)d_in[3];
  const float* wkr = (const float*)d_in[4];
  const float* wki = (const float*)d_in[5];
  const float* wvr = (const float*)d_in[6];
  const float* wvi = (const float*)d_in[7];

  float* outR = (float*)d_out;                       // [4,4096,256]
  float* outI = outR + (size_t)4 * 4096 * 256;       // [4,4096,256]
  float* attn = outI + (size_t)4 * 4096 * 256;       // [4,4096,4096] raw -> normalized

  char* ws = (char*)d_ws;
  f16* X  = (f16*)ws;                                              // 16 MB (dead after proj -> stats)
  f16* W  = (f16*)(ws + (size_t)16384 * 512 * 2);                  // 1.5 MB (dead after proj -> ml)
  f16* P  = (f16*)(ws + (size_t)16384 * 512 * 2 + (size_t)1536 * 512 * 2);  // [16384,1536] 48 MB
  f16* VT = (f16*)(ws + (size_t)16384 * 512 * 2 + (size_t)1536 * 512 * 2 +
                   (size_t)16384 * 1536 * 2);                      // [4,512,4096]  16 MB
  float2* stats = (float2*)X;                                      // [64][16384]   8 MB
  float2* ml    = (float2*)W;                                      // [16384]       128 KB

  build_x<<<8192, 256, 0, stream>>>(qr, qi, X);
  build_w<<<768, 256, 0, stream>>>(wqr, wqi, wkr, wki, wvr, wvi, W);

  // P = X @ Wbig^T : M=16384, N=1536, K=512
  gemm_nt<0><<<dim3(12, 128, 1), 256, 0, stream>>>(X, 512, 0L, W, 512, 0L, 512, 1.0f,
                                                   (void*)P, 0L, nullptr);

  build_vt<<<dim3(64, 8, 4), 256, 0, stream>>>(P, VT);

  // raw scores + per-tile stats : per batch M=N=4096, K=512
  gemm_nt<1><<<dim3(32, 32, 4), 256, 0, stream>>>(P, 1536, (long)4096 * 1536,
                                                  P + 512, 1536, (long)4096 * 1536,
                                                  512, 0.0625f,
                                                  (void*)attn, (long)4096 * 4096, stats);

  merge_stats<<<64, 256, 0, stream>>>(stats, ml);

  // fused normalize + PV (pipelined)
  pv_fused<<<dim3(64, 4, 1), 512, 0, stream>>>(ml, attn, VT, outR, outI);
}